// Round 3
// baseline (335.315 us; speedup 1.0000x reference)
//
#include <hip/hip_runtime.h>
#include <hip/hip_bf16.h>
#include <stdint.h>

// CausalAttention fused block, MI355X gfx950.
// R2: attention occupancy fix — 4-wave blocks over complementary q-tile pairs
// (uniform 17 key-blocks/pair), 4-way key-split per tile with LDS partial
// merge (no-max softmax => merge is a pure add). Inner math identical to R1.
// GEMMs unchanged (m97-style 128x128 bf16 MFMA).

typedef __bf16 bf16;
typedef __attribute__((ext_vector_type(4))) __bf16 bf16x4;
typedef __attribute__((ext_vector_type(8))) __bf16 bf16x8;
typedef __attribute__((ext_vector_type(4))) float f32x4;

#define NB 8
#define NT 1024
#define NC 768
#define NH 12
#define ND 64
#define NM (NB*NT)     // 8192
#define N3C (3*NC)     // 2304

typedef __attribute__((address_space(1))) void as1_void;
typedef __attribute__((address_space(3))) void as3_void;

__device__ __forceinline__ void gload_lds16(const void* g, void* l) {
  __builtin_amdgcn_global_load_lds((as1_void*)g, (as3_void*)l, 16, 0, 0);
}

// ---------------- prep: f32 -> bf16 convert (vectorized) ----------------
__global__ void k_convert(const float* __restrict__ src, bf16* __restrict__ dst, int n4) {
  int i = blockIdx.x * blockDim.x + threadIdx.x;
  if (i < n4) {
    float4 v = reinterpret_cast<const float4*>(src)[i];
    bf16x4 o = { (bf16)v.x, (bf16)v.y, (bf16)v.z, (bf16)v.w };
    reinterpret_cast<bf16x4*>(dst)[i] = o;
  }
}

// ---------------- prep: W [R][C] f32 -> W^T [C][R] bf16 ----------------
__global__ void k_transpose_w(const float* __restrict__ src, bf16* __restrict__ dst,
                              int R, int C) {
  __shared__ float tile[32][33];
  const int c0 = blockIdx.x * 32, r0 = blockIdx.y * 32;
  const int tx = threadIdx.x & 31, ty = threadIdx.x >> 5;  // 256 thr: ty 0..7
#pragma unroll
  for (int i = 0; i < 4; i++)
    tile[ty + i*8][tx] = src[(size_t)(r0 + ty + i*8) * C + c0 + tx];
  __syncthreads();
#pragma unroll
  for (int i = 0; i < 4; i++)
    dst[(size_t)(c0 + ty + i*8) * R + r0 + tx] = (bf16)tile[tx][ty + i*8];
}

// ---------------- m97-style 128x128 bf16 GEMM, B^T input ----------------
// C[M][N] = A[M][K] @ Bt[N][K]^T + bias ; 256 thr = 4 waves, 64x64 per wave.
template<bool OUT_BF16>
__global__ void k_gemm_bt(const bf16* __restrict__ A, const bf16* __restrict__ Bt,
                          const float* __restrict__ bias, void* __restrict__ Cout,
                          int M, int N, int K) {
  __shared__ __align__(16) bf16 As[128*32];
  __shared__ __align__(16) bf16 Bs[128*32];
  const int tm = blockIdx.x * 128, tn = blockIdx.y * 128;
  const int tid = threadIdx.x, lane = tid & 63, w = tid >> 6;
  const int wr = w >> 1, wc = w & 1;
  const int lr = lane & 15, lhi = lane >> 4;
  const int srow = tid >> 2, scol = (tid & 3) * 8;

  f32x4 acc[4][4];
#pragma unroll
  for (int m = 0; m < 4; m++)
#pragma unroll
    for (int n = 0; n < 4; n++) acc[m][n] = (f32x4){0.f, 0.f, 0.f, 0.f};

  for (int kt = 0; kt < K; kt += 32) {
    __syncthreads();  // protect LDS from overwrite while prior reads in flight
#pragma unroll
    for (int ch = 0; ch < 2; ch++) {
      gload_lds16(A + (size_t)(tm + ch*64 + srow) * K + kt + scol,
                  (char*)As + ch*4096 + tid*16);
      gload_lds16(Bt + (size_t)(tn + ch*64 + srow) * K + kt + scol,
                  (char*)Bs + ch*4096 + tid*16);
    }
    __syncthreads();  // drains vmcnt (global_load_lds) per gfx950 semantics

    bf16x8 af[4], bfr[4];
#pragma unroll
    for (int m = 0; m < 4; m++)
      af[m] = *reinterpret_cast<const bf16x8*>(
          (const char*)As + (wr*64 + m*16 + lr) * 64 + lhi * 16);
#pragma unroll
    for (int n = 0; n < 4; n++)
      bfr[n] = *reinterpret_cast<const bf16x8*>(
          (const char*)Bs + (wc*64 + n*16 + lr) * 64 + lhi * 16);
#pragma unroll
    for (int m = 0; m < 4; m++)
#pragma unroll
      for (int n = 0; n < 4; n++)
        acc[m][n] = __builtin_amdgcn_mfma_f32_16x16x32_bf16(af[m], bfr[n], acc[m][n], 0, 0, 0);
  }

#pragma unroll
  for (int m = 0; m < 4; m++)
#pragma unroll
    for (int n = 0; n < 4; n++) {
      const int col = tn + wc*64 + n*16 + lr;
      const float bv = bias[col];
#pragma unroll
      for (int j = 0; j < 4; j++) {
        const int row = tm + wr*64 + m*16 + lhi*4 + j;
        const float v = acc[m][n][j] + bv;
        if (OUT_BF16) ((bf16*)Cout)[(size_t)row * N + col] = (bf16)v;
        else          ((float*)Cout)[(size_t)row * N + col] = v;
      }
    }
}

// ---------------- V^T: qkv v-part [b,t,h,d] -> vt [bh][d][t] bf16 ----------------
__global__ void k_make_vt(const bf16* __restrict__ qkv, bf16* __restrict__ vt) {
  const int bh = blockIdx.x, b = bh / NH, h = bh % NH;
  const int t0 = blockIdx.y * 64;
  __shared__ bf16 tile[64][72];  // [t][d], padded
  const int tx = threadIdx.x & 15, ty = threadIdx.x >> 4;
#pragma unroll
  for (int i = 0; i < 4; i++) {
    const int t = ty + i*16;
    bf16x4 v = *reinterpret_cast<const bf16x4*>(
        qkv + (size_t)(b*NT + t0 + t) * N3C + 2*NC + h*ND + tx*4);
#pragma unroll
    for (int j = 0; j < 4; j++) tile[t][tx*4 + j] = v[j];
  }
  __syncthreads();
#pragma unroll
  for (int i = 0; i < 4; i++) {
    const int d = ty + i*16;
    bf16x4 v;
#pragma unroll
    for (int j = 0; j < 4; j++) v[j] = tile[tx*4 + j][d];
    *reinterpret_cast<bf16x4*>(vt + ((size_t)bh*ND + d) * NT + t0 + tx*4) = v;
  }
}

// ---------------- flash attention, causal, no-max online softmax ----------------
// R2: block = 4 waves, one complementary q-tile pair (qt=p, 31-p): exactly 17
// key-blocks of work per block. Waves split key-blocks 4-way, accumulate
// partial (O,L), merge via LDS atomicAdd (no-max => pure add), cooperative
// normalize + store. K/V from L2; P bounced through padded per-wave LDS tile.
__global__ void __launch_bounds__(256, 4)
k_attn(const bf16* __restrict__ qkv, const bf16* __restrict__ vt,
       bf16* __restrict__ y) {
  const int bh = blockIdx.x, b = bh / NH, h = bh % NH;
  const int p = blockIdx.y;            // pair index 0..15
  const int tid = threadIdx.x, w = tid >> 6, lane = tid & 63;
  const int lr = lane & 15, lhi = lane >> 4;

  __shared__ __align__(16) bf16 P[4][32][68];     // per-wave P tile (17,408 B)
  __shared__ __align__(16) float Obuf[2][32][68]; // merge buf, stride 68 (17,408 B)
  __shared__ float Lbuf[2][32];

  for (int i = tid; i < 2*32*68; i += 256) ((float*)Obuf)[i] = 0.f;
  if (tid < 64) ((float*)Lbuf)[tid] = 0.f;
  __syncthreads();

#pragma unroll 1
  for (int tile = 0; tile < 2; tile++) {
    const int qt = tile ? (31 - p) : p;
    const int qbase = qt * 32;
    const int nkb = (qbase >> 6) + 1;  // 64-key blocks; covers keys <= row max

    bf16x8 qf[2][2];
#pragma unroll
    for (int m = 0; m < 2; m++)
#pragma unroll
      for (int kk = 0; kk < 2; kk++)
        qf[m][kk] = *reinterpret_cast<const bf16x8*>(
            qkv + (size_t)(b*NT + qbase + m*16 + lr) * N3C + NC + h*ND + kk*32 + lhi*8);

    f32x4 O[2][4];
    float L[2][4];
#pragma unroll
    for (int m = 0; m < 2; m++) {
#pragma unroll
      for (int d = 0; d < 4; d++) O[m][d] = (f32x4){0.f, 0.f, 0.f, 0.f};
#pragma unroll
      for (int j = 0; j < 4; j++) L[m][j] = 0.f;
    }

    for (int kb = w; kb < nkb; kb += 4) {   // 4-way key-split across waves
      const int k0 = kb * 64;
      f32x4 S[2][4];
#pragma unroll
      for (int m = 0; m < 2; m++)
#pragma unroll
        for (int g = 0; g < 4; g++) S[m][g] = (f32x4){0.f, 0.f, 0.f, 0.f};

#pragma unroll
      for (int g = 0; g < 4; g++) {
        const bf16* kp = qkv + (size_t)(b*NT + k0 + g*16 + lr) * N3C + h*ND;
        bf16x8 kf0 = *reinterpret_cast<const bf16x8*>(kp + lhi*8);
        bf16x8 kf1 = *reinterpret_cast<const bf16x8*>(kp + 32 + lhi*8);
#pragma unroll
        for (int m = 0; m < 2; m++) {
          S[m][g] = __builtin_amdgcn_mfma_f32_16x16x32_bf16(qf[m][0], kf0, S[m][g], 0, 0, 0);
          S[m][g] = __builtin_amdgcn_mfma_f32_16x16x32_bf16(qf[m][1], kf1, S[m][g], 0, 0, 0);
        }
      }

      // prefetch V for this key block (overlaps with exp/store below)
      bf16x8 vf[4][2];
#pragma unroll
      for (int dg = 0; dg < 4; dg++)
#pragma unroll
        for (int kk = 0; kk < 2; kk++)
          vf[dg][kk] = *reinterpret_cast<const bf16x8*>(
              vt + ((size_t)bh*ND + dg*16 + lr) * NT + k0 + kk*32 + lhi*8);

      const bool need_mask = (kb == nkb - 1);
#pragma unroll
      for (int m = 0; m < 2; m++)
#pragma unroll
        for (int g = 0; g < 4; g++) {
          const int key = k0 + g*16 + lr;
#pragma unroll
          for (int j = 0; j < 4; j++) {
            float s = S[m][g][j];
            if (need_mask) {
              const int row = qbase + m*16 + lhi*4 + j;
              if (key > row) s = -1e30f;
            }
            const float ppv = __expf(s);   // no-max softmax: s <= ~15, f32-safe
            L[m][j] += ppv;
            P[w][m*16 + lhi*4 + j][g*16 + lr] = (bf16)ppv;
          }
        }

#pragma unroll
      for (int m = 0; m < 2; m++) {
#pragma unroll
        for (int kk = 0; kk < 2; kk++) {
          bf16x8 pf = *reinterpret_cast<const bf16x8*>(&P[w][m*16 + lr][kk*32 + lhi*8]);
#pragma unroll
          for (int dg = 0; dg < 4; dg++)
            O[m][dg] = __builtin_amdgcn_mfma_f32_16x16x32_bf16(pf, vf[dg][kk], O[m][dg], 0, 0, 0);
        }
      }
    }

    // complete per-wave row sums of L across the 16 lr lanes
#pragma unroll
    for (int m = 0; m < 2; m++)
#pragma unroll
      for (int j = 0; j < 4; j++) {
        float l = L[m][j];
        l += __shfl_xor(l, 1);
        l += __shfl_xor(l, 2);
        l += __shfl_xor(l, 4);
        l += __shfl_xor(l, 8);
        L[m][j] = l;
      }

    // merge partials into LDS (pure add thanks to no-max softmax)
#pragma unroll
    for (int m = 0; m < 2; m++)
#pragma unroll
      for (int dg = 0; dg < 4; dg++)
#pragma unroll
        for (int j = 0; j < 4; j++)
          atomicAdd(&Obuf[tile][m*16 + lhi*4 + j][dg*16 + lr], O[m][dg][j]);
    if (lr == 0)
#pragma unroll
      for (int m = 0; m < 2; m++)
#pragma unroll
        for (int j = 0; j < 4; j++)
          atomicAdd(&Lbuf[tile][m*16 + lhi*4 + j], L[m][j]);

    __syncthreads();  // all waves' adds for this tile complete

    // cooperative normalize + store: thread -> (q = tid/8, 8 dv cols)
    {
      const int q = tid >> 3, dvb = (tid & 7) * 8;
      const float invl = 1.0f / Lbuf[tile][q];
      bf16x8 ov;
#pragma unroll
      for (int i = 0; i < 8; i++)
        ov[i] = (bf16)(Obuf[tile][q][dvb + i] * invl);
      *reinterpret_cast<bf16x8*>(
          y + (size_t)(b*NT + qbase + q) * NC + h*ND + dvb) = ov;
    }
    // no barrier needed: next tile uses the other Obuf/Lbuf slot
  }
}

// ---------------- launcher ----------------
extern "C" void kernel_launch(void* const* d_in, const int* in_sizes, int n_in,
                              void* d_out, int out_size, void* d_ws, size_t ws_size,
                              hipStream_t stream) {
  const float* x     = (const float*)d_in[0];
  const float* W_in  = (const float*)d_in[1];
  const float* b_in  = (const float*)d_in[2];
  const float* W_out = (const float*)d_in[3];
  const float* b_out = (const float*)d_in[4];
  float* out = (float*)d_out;
  char* ws = (char*)d_ws;

  // workspace layout (bytes, 16-aligned); xb region is reused as y after GEMM1
  bf16* xb  = (bf16*)(ws + 0);          // 8192*768   bf16 = 12,582,912  (later: y)
  bf16* Wit = (bf16*)(ws + 12582912);   // 2304*768   bf16 =  3,538,944
  bf16* Wot = (bf16*)(ws + 16121856);   //  768*768   bf16 =  1,179,648
  bf16* qkv = (bf16*)(ws + 17301504);   // 8192*2304  bf16 = 37,748,736
  bf16* vt  = (bf16*)(ws + 55050240);   // 96*64*1024 bf16 = 12,582,912
  // total 67,633,152 bytes

  k_convert<<<6144, 256, 0, stream>>>(x, xb, NM * NC / 4);
  k_transpose_w<<<dim3(N3C/32, NC/32), 256, 0, stream>>>(W_in, Wit, NC, N3C);
  k_transpose_w<<<dim3(NC/32, NC/32), 256, 0, stream>>>(W_out, Wot, NC, NC);

  k_gemm_bt<true><<<dim3(NM/128, N3C/128), 256, 0, stream>>>(
      xb, Wit, b_in, qkv, NM, N3C, NC);

  k_make_vt<<<dim3(NB*NH, NT/64), 256, 0, stream>>>(qkv, vt);

  k_attn<<<dim3(NB*NH, 16), 256, 0, stream>>>(qkv, vt, xb /* y */);

  k_gemm_bt<false><<<dim3(NM/128, NC/128), 256, 0, stream>>>(
      xb, Wot, b_out, out, NM, NC, NC);
}

// Round 5
// 316.516 us; speedup vs baseline: 1.0594x; 1.0594x over previous
//
#include <hip/hip_runtime.h>
#include <hip/hip_bf16.h>
#include <stdint.h>

// CausalAttention fused block, MI355X gfx950.
// R3 (resubmit after broker timeout): attention = 1-wave blocks over
// complementary q-tile pairs (uniform 17 iterations/block), register
// double-buffered K prefetch pipeline (ping-pong, no launch_bounds cap —
// R2's spill lesson). GEMMs unchanged (m97-style).

typedef __bf16 bf16;
typedef __attribute__((ext_vector_type(4))) __bf16 bf16x4;
typedef __attribute__((ext_vector_type(8))) __bf16 bf16x8;
typedef __attribute__((ext_vector_type(4))) float f32x4;

#define NB 8
#define NT 1024
#define NC 768
#define NH 12
#define ND 64
#define NM (NB*NT)     // 8192
#define N3C (3*NC)     // 2304

typedef __attribute__((address_space(1))) void as1_void;
typedef __attribute__((address_space(3))) void as3_void;

__device__ __forceinline__ void gload_lds16(const void* g, void* l) {
  __builtin_amdgcn_global_load_lds((as1_void*)g, (as3_void*)l, 16, 0, 0);
}

// ---------------- prep: f32 -> bf16 convert (vectorized) ----------------
__global__ void k_convert(const float* __restrict__ src, bf16* __restrict__ dst, int n4) {
  int i = blockIdx.x * blockDim.x + threadIdx.x;
  if (i < n4) {
    float4 v = reinterpret_cast<const float4*>(src)[i];
    bf16x4 o = { (bf16)v.x, (bf16)v.y, (bf16)v.z, (bf16)v.w };
    reinterpret_cast<bf16x4*>(dst)[i] = o;
  }
}

// ---------------- prep: W [R][C] f32 -> W^T [C][R] bf16 ----------------
__global__ void k_transpose_w(const float* __restrict__ src, bf16* __restrict__ dst,
                              int R, int C) {
  __shared__ float tile[32][33];
  const int c0 = blockIdx.x * 32, r0 = blockIdx.y * 32;
  const int tx = threadIdx.x & 31, ty = threadIdx.x >> 5;  // 256 thr: ty 0..7
#pragma unroll
  for (int i = 0; i < 4; i++)
    tile[ty + i*8][tx] = src[(size_t)(r0 + ty + i*8) * C + c0 + tx];
  __syncthreads();
#pragma unroll
  for (int i = 0; i < 4; i++)
    dst[(size_t)(c0 + ty + i*8) * R + r0 + tx] = (bf16)tile[tx][ty + i*8];
}

// ---------------- m97-style 128x128 bf16 GEMM, B^T input ----------------
// C[M][N] = A[M][K] @ Bt[N][K]^T + bias ; 256 thr = 4 waves, 64x64 per wave.
template<bool OUT_BF16>
__global__ void k_gemm_bt(const bf16* __restrict__ A, const bf16* __restrict__ Bt,
                          const float* __restrict__ bias, void* __restrict__ Cout,
                          int M, int N, int K) {
  __shared__ __align__(16) bf16 As[128*32];
  __shared__ __align__(16) bf16 Bs[128*32];
  const int tm = blockIdx.x * 128, tn = blockIdx.y * 128;
  const int tid = threadIdx.x, lane = tid & 63, w = tid >> 6;
  const int wr = w >> 1, wc = w & 1;
  const int lr = lane & 15, lhi = lane >> 4;
  const int srow = tid >> 2, scol = (tid & 3) * 8;

  f32x4 acc[4][4];
#pragma unroll
  for (int m = 0; m < 4; m++)
#pragma unroll
    for (int n = 0; n < 4; n++) acc[m][n] = (f32x4){0.f, 0.f, 0.f, 0.f};

  for (int kt = 0; kt < K; kt += 32) {
    __syncthreads();  // protect LDS from overwrite while prior reads in flight
#pragma unroll
    for (int ch = 0; ch < 2; ch++) {
      gload_lds16(A + (size_t)(tm + ch*64 + srow) * K + kt + scol,
                  (char*)As + ch*4096 + tid*16);
      gload_lds16(Bt + (size_t)(tn + ch*64 + srow) * K + kt + scol,
                  (char*)Bs + ch*4096 + tid*16);
    }
    __syncthreads();  // drains vmcnt (global_load_lds) per gfx950 semantics

    bf16x8 af[4], bfr[4];
#pragma unroll
    for (int m = 0; m < 4; m++)
      af[m] = *reinterpret_cast<const bf16x8*>(
          (const char*)As + (wr*64 + m*16 + lr) * 64 + lhi * 16);
#pragma unroll
    for (int n = 0; n < 4; n++)
      bfr[n] = *reinterpret_cast<const bf16x8*>(
          (const char*)Bs + (wc*64 + n*16 + lr) * 64 + lhi * 16);
#pragma unroll
    for (int m = 0; m < 4; m++)
#pragma unroll
      for (int n = 0; n < 4; n++)
        acc[m][n] = __builtin_amdgcn_mfma_f32_16x16x32_bf16(af[m], bfr[n], acc[m][n], 0, 0, 0);
  }

#pragma unroll
  for (int m = 0; m < 4; m++)
#pragma unroll
    for (int n = 0; n < 4; n++) {
      const int col = tn + wc*64 + n*16 + lr;
      const float bv = bias[col];
#pragma unroll
      for (int j = 0; j < 4; j++) {
        const int row = tm + wr*64 + m*16 + lhi*4 + j;
        const float v = acc[m][n][j] + bv;
        if (OUT_BF16) ((bf16*)Cout)[(size_t)row * N + col] = (bf16)v;
        else          ((float*)Cout)[(size_t)row * N + col] = v;
      }
    }
}

// ---------------- V^T: qkv v-part [b,t,h,d] -> vt [bh][d][t] bf16 ----------------
__global__ void k_make_vt(const bf16* __restrict__ qkv, bf16* __restrict__ vt) {
  const int bh = blockIdx.x, b = bh / NH, h = bh % NH;
  const int t0 = blockIdx.y * 64;
  __shared__ bf16 tile[64][72];  // [t][d], padded
  const int tx = threadIdx.x & 15, ty = threadIdx.x >> 4;
#pragma unroll
  for (int i = 0; i < 4; i++) {
    const int t = ty + i*16;
    bf16x4 v = *reinterpret_cast<const bf16x4*>(
        qkv + (size_t)(b*NT + t0 + t) * N3C + 2*NC + h*ND + tx*4);
#pragma unroll
    for (int j = 0; j < 4; j++) tile[t][tx*4 + j] = v[j];
  }
  __syncthreads();
#pragma unroll
  for (int i = 0; i < 4; i++) {
    const int d = ty + i*16;
    bf16x4 v;
#pragma unroll
    for (int j = 0; j < 4; j++) v[j] = tile[tx*4 + j][d];
    *reinterpret_cast<bf16x4*>(vt + ((size_t)bh*ND + d) * NT + t0 + tx*4) = v;
  }
}

// ---------------- flash attention, causal, no-max online softmax ----------------
// R3: one wave per block; block handles q-tiles p and 31-p sequentially
// (17 key-block iterations total for every p -> uniform). K register
// double-buffer ping-pong hides K latency; V loads issued at phase top hide
// under QK+exp. P bounced through padded LDS tile (conflict-free).
__global__ void k_attn(const bf16* __restrict__ qkv, const bf16* __restrict__ vt,
                       bf16* __restrict__ y) {
  const int bh = blockIdx.x, b = bh / NH, h = bh % NH;
  const int p = blockIdx.y;            // pair index 0..15
  const int lane = threadIdx.x;
  const int lr = lane & 15, lhi = lane >> 4;
  __shared__ __align__(16) bf16 P[32][68];  // stride 136B: conflict-free

#define LOAD_K(DST, K0)                                                        \
  {                                                                            \
    _Pragma("unroll")                                                          \
    for (int g = 0; g < 4; g++) {                                              \
      const bf16* kp = qkv + (size_t)(b*NT + (K0) + g*16 + lr) * N3C + h*ND;   \
      DST[g][0] = *reinterpret_cast<const bf16x8*>(kp + lhi*8);                \
      DST[g][1] = *reinterpret_cast<const bf16x8*>(kp + 32 + lhi*8);           \
    }                                                                          \
  }

#define ATTN_STEP(KCUR, KNXT, KB)                                              \
  {                                                                            \
    const int k0 = (KB) * 64;                                                  \
    const int kn = ((KB) + 1 < nkb) ? k0 + 64 : k0;                            \
    /* V loads for current tile — land under QK+exp */                         \
    bf16x8 vf[4][2];                                                           \
    _Pragma("unroll")                                                          \
    for (int dg = 0; dg < 4; dg++)                                             \
      _Pragma("unroll")                                                        \
      for (int kk = 0; kk < 2; kk++)                                           \
        vf[dg][kk] = *reinterpret_cast<const bf16x8*>(                         \
            vt + ((size_t)bh*ND + dg*16 + lr) * NT + k0 + kk*32 + lhi*8);      \
    /* prefetch next K tile — lands under the whole iteration */               \
    LOAD_K(KNXT, kn);                                                          \
    f32x4 S[2][4];                                                             \
    _Pragma("unroll")                                                          \
    for (int m = 0; m < 2; m++)                                                \
      _Pragma("unroll")                                                        \
      for (int g = 0; g < 4; g++) S[m][g] = (f32x4){0.f, 0.f, 0.f, 0.f};       \
    _Pragma("unroll")                                                          \
    for (int g = 0; g < 4; g++)                                                \
      _Pragma("unroll")                                                        \
      for (int m = 0; m < 2; m++) {                                            \
        S[m][g] = __builtin_amdgcn_mfma_f32_16x16x32_bf16(qf[m][0], KCUR[g][0],\
                                                          S[m][g], 0, 0, 0);   \
        S[m][g] = __builtin_amdgcn_mfma_f32_16x16x32_bf16(qf[m][1], KCUR[g][1],\
                                                          S[m][g], 0, 0, 0);   \
      }                                                                        \
    const bool need_mask = ((KB) == nkb - 1);                                  \
    _Pragma("unroll")                                                          \
    for (int m = 0; m < 2; m++)                                                \
      _Pragma("unroll")                                                        \
      for (int g = 0; g < 4; g++) {                                            \
        const int key = k0 + g*16 + lr;                                        \
        _Pragma("unroll")                                                      \
        for (int j = 0; j < 4; j++) {                                          \
          float s = S[m][g][j];                                                \
          if (need_mask) {                                                     \
            const int row = qbase + m*16 + lhi*4 + j;                          \
            if (key > row) s = -1e30f;                                         \
          }                                                                    \
          const float ppv = __expf(s);  /* no-max softmax: s<=~15, f32-safe */ \
          L[m][j] += ppv;                                                      \
          P[m*16 + lhi*4 + j][g*16 + lr] = (bf16)ppv;                          \
        }                                                                      \
      }                                                                        \
    _Pragma("unroll")                                                          \
    for (int m = 0; m < 2; m++)                                                \
      _Pragma("unroll")                                                        \
      for (int kk = 0; kk < 2; kk++) {                                         \
        bf16x8 pf = *reinterpret_cast<const bf16x8*>(&P[m*16 + lr][kk*32 + lhi*8]); \
        _Pragma("unroll")                                                      \
        for (int dg = 0; dg < 4; dg++)                                         \
          O[m][dg] = __builtin_amdgcn_mfma_f32_16x16x32_bf16(pf, vf[dg][kk],   \
                                                             O[m][dg], 0, 0, 0); \
      }                                                                        \
  }

#pragma unroll 1
  for (int half = 0; half < 2; half++) {
    const int qt = half ? (31 - p) : p;
    const int qbase = qt * 32;
    const int nkb = (qbase >> 6) + 1;  // 64-key blocks; covers keys <= row max

    bf16x8 qf[2][2];
#pragma unroll
    for (int m = 0; m < 2; m++)
#pragma unroll
      for (int kk = 0; kk < 2; kk++)
        qf[m][kk] = *reinterpret_cast<const bf16x8*>(
            qkv + (size_t)(b*NT + qbase + m*16 + lr) * N3C + NC + h*ND + kk*32 + lhi*8);

    f32x4 O[2][4];
    float L[2][4];
#pragma unroll
    for (int m = 0; m < 2; m++) {
#pragma unroll
      for (int d = 0; d < 4; d++) O[m][d] = (f32x4){0.f, 0.f, 0.f, 0.f};
#pragma unroll
      for (int j = 0; j < 4; j++) L[m][j] = 0.f;
    }

    bf16x8 kfA[4][2], kfB[4][2];
    LOAD_K(kfA, 0);
    int kb = 0;
#pragma unroll 1
    while (true) {
      ATTN_STEP(kfA, kfB, kb);
      kb++;
      if (kb >= nkb) break;
      ATTN_STEP(kfB, kfA, kb);
      kb++;
      if (kb >= nkb) break;
    }

    // reduce L over the 16 lr lanes of each row group, then invert
#pragma unroll
    for (int m = 0; m < 2; m++)
#pragma unroll
      for (int j = 0; j < 4; j++) {
        float l = L[m][j];
        l += __shfl_xor(l, 1);
        l += __shfl_xor(l, 2);
        l += __shfl_xor(l, 4);
        l += __shfl_xor(l, 8);
        L[m][j] = 1.0f / l;
      }

#pragma unroll
    for (int m = 0; m < 2; m++)
#pragma unroll
      for (int dg = 0; dg < 4; dg++)
#pragma unroll
        for (int j = 0; j < 4; j++) {
          const int row = qbase + m*16 + lhi*4 + j;
          const int col = h*ND + dg*16 + lr;
          y[(size_t)(b*NT + row) * NC + col] = (bf16)(O[m][dg][j] * L[m][j]);
        }
  }
#undef ATTN_STEP
#undef LOAD_K
}

// ---------------- launcher ----------------
extern "C" void kernel_launch(void* const* d_in, const int* in_sizes, int n_in,
                              void* d_out, int out_size, void* d_ws, size_t ws_size,
                              hipStream_t stream) {
  const float* x     = (const float*)d_in[0];
  const float* W_in  = (const float*)d_in[1];
  const float* b_in  = (const float*)d_in[2];
  const float* W_out = (const float*)d_in[3];
  const float* b_out = (const float*)d_in[4];
  float* out = (float*)d_out;
  char* ws = (char*)d_ws;

  // workspace layout (bytes, 16-aligned); xb region is reused as y after GEMM1
  bf16* xb  = (bf16*)(ws + 0);          // 8192*768   bf16 = 12,582,912  (later: y)
  bf16* Wit = (bf16*)(ws + 12582912);   // 2304*768   bf16 =  3,538,944
  bf16* Wot = (bf16*)(ws + 16121856);   //  768*768   bf16 =  1,179,648
  bf16* qkv = (bf16*)(ws + 17301504);   // 8192*2304  bf16 = 37,748,736
  bf16* vt  = (bf16*)(ws + 55050240);   // 96*64*1024 bf16 = 12,582,912
  // total 67,633,152 bytes

  k_convert<<<6144, 256, 0, stream>>>(x, xb, NM * NC / 4);
  k_transpose_w<<<dim3(N3C/32, NC/32), 256, 0, stream>>>(W_in, Wit, NC, N3C);
  k_transpose_w<<<dim3(NC/32, NC/32), 256, 0, stream>>>(W_out, Wot, NC, NC);

  k_gemm_bt<true><<<dim3(NM/128, N3C/128), 256, 0, stream>>>(
      xb, Wit, b_in, qkv, NM, N3C, NC);

  k_make_vt<<<dim3(NB*NH, NT/64), 256, 0, stream>>>(qkv, vt);

  k_attn<<<dim3(NB*NH, 16), 64, 0, stream>>>(qkv, vt, xb /* y */);

  k_gemm_bt<false><<<dim3(NM/128, NC/128), 256, 0, stream>>>(
      xb, Wot, b_out, out, NM, NC, NC);
}

// Round 6
// 202.248 us; speedup vs baseline: 1.6579x; 1.5650x over previous
//
#include <hip/hip_runtime.h>
#include <hip/hip_bf16.h>
#include <stdint.h>

// CausalAttention fused block, MI355X gfx950.
// R5: (a) GEMM1 epilogue writes Q/K/V directly in MFMA-fragment-packed
// layouts (all attention global loads become fully coalesced 1KB streams;
// k_make_vt deleted); (b) attention keeps uniform pair-blocks + K ping-pong
// but now with __launch_bounds__(64,2) so the allocator gets a 256-VGPR
// budget (R2/R3 lesson: unbounded kernels get clamped to 64 and spill).

typedef __bf16 bf16;
typedef __attribute__((ext_vector_type(4))) __bf16 bf16x4;
typedef __attribute__((ext_vector_type(8))) __bf16 bf16x8;
typedef __attribute__((ext_vector_type(4))) float f32x4;

#define NB 8
#define NT 1024
#define NC 768
#define NH 12
#define ND 64
#define NM (NB*NT)     // 8192
#define N3C (3*NC)     // 2304

typedef __attribute__((address_space(1))) void as1_void;
typedef __attribute__((address_space(3))) void as3_void;

__device__ __forceinline__ void gload_lds16(const void* g, void* l) {
  __builtin_amdgcn_global_load_lds((as1_void*)g, (as3_void*)l, 16, 0, 0);
}

// Packed fragment layouts (elements, bf16):
//  kpack/qpack: frag(bh, g16 = t/16, h2 = d/32) lane l = (d%32/8)*16 + t%16,
//               elem j = d%8  -> idx = ((bh*64 + g16)*2 + h2)*512 + l*8 + j
//  vpack: frag(bh, vb = t/64, dg = d/16, kk = (t/32)%2) lane l = (d%16) +
//               ((t/8)%4)*16, elem j = t%8
//               -> idx = (((bh*16+vb)*4+dg)*2+kk)*512 + l*8 + j

// ---------------- prep: f32 -> bf16 convert (vectorized) ----------------
__global__ void k_convert(const float* __restrict__ src, bf16* __restrict__ dst, int n4) {
  int i = blockIdx.x * blockDim.x + threadIdx.x;
  if (i < n4) {
    float4 v = reinterpret_cast<const float4*>(src)[i];
    bf16x4 o = { (bf16)v.x, (bf16)v.y, (bf16)v.z, (bf16)v.w };
    reinterpret_cast<bf16x4*>(dst)[i] = o;
  }
}

// ---------------- prep: W [R][C] f32 -> W^T [C][R] bf16 ----------------
__global__ void k_transpose_w(const float* __restrict__ src, bf16* __restrict__ dst,
                              int R, int C) {
  __shared__ float tile[32][33];
  const int c0 = blockIdx.x * 32, r0 = blockIdx.y * 32;
  const int tx = threadIdx.x & 31, ty = threadIdx.x >> 5;  // 256 thr: ty 0..7
#pragma unroll
  for (int i = 0; i < 4; i++)
    tile[ty + i*8][tx] = src[(size_t)(r0 + ty + i*8) * C + c0 + tx];
  __syncthreads();
#pragma unroll
  for (int i = 0; i < 4; i++)
    dst[(size_t)(c0 + ty + i*8) * R + r0 + tx] = (bf16)tile[tx][ty + i*8];
}

// ---------------- m97-style 128x128 bf16 GEMM, B^T input ----------------
// MODE 0: C[M][N] (f32) = A@Bt^T + bias   (GEMM2)
// MODE 1: scatter into qpack/kpack/vpack (bf16) + bias  (GEMM1)
template<int MODE>
__global__ void k_gemm_bt(const bf16* __restrict__ A, const bf16* __restrict__ Bt,
                          const float* __restrict__ bias, float* __restrict__ Cout,
                          bf16* __restrict__ qp, bf16* __restrict__ kp,
                          bf16* __restrict__ vp,
                          int M, int N, int K) {
  __shared__ __align__(16) bf16 As[128*32];
  __shared__ __align__(16) bf16 Bs[128*32];
  const int tm = blockIdx.x * 128, tn = blockIdx.y * 128;
  const int tid = threadIdx.x, lane = tid & 63, w = tid >> 6;
  const int wr = w >> 1, wc = w & 1;
  const int lr = lane & 15, lhi = lane >> 4;
  const int srow = tid >> 2, scol = (tid & 3) * 8;

  f32x4 acc[4][4];
#pragma unroll
  for (int m = 0; m < 4; m++)
#pragma unroll
    for (int n = 0; n < 4; n++) acc[m][n] = (f32x4){0.f, 0.f, 0.f, 0.f};

  for (int kt = 0; kt < K; kt += 32) {
    __syncthreads();  // protect LDS from overwrite while prior reads in flight
#pragma unroll
    for (int ch = 0; ch < 2; ch++) {
      gload_lds16(A + (size_t)(tm + ch*64 + srow) * K + kt + scol,
                  (char*)As + ch*4096 + tid*16);
      gload_lds16(Bt + (size_t)(tn + ch*64 + srow) * K + kt + scol,
                  (char*)Bs + ch*4096 + tid*16);
    }
    __syncthreads();  // drains vmcnt (global_load_lds) per gfx950 semantics

    bf16x8 af[4], bfr[4];
#pragma unroll
    for (int m = 0; m < 4; m++)
      af[m] = *reinterpret_cast<const bf16x8*>(
          (const char*)As + (wr*64 + m*16 + lr) * 64 + lhi * 16);
#pragma unroll
    for (int n = 0; n < 4; n++)
      bfr[n] = *reinterpret_cast<const bf16x8*>(
          (const char*)Bs + (wc*64 + n*16 + lr) * 64 + lhi * 16);
#pragma unroll
    for (int m = 0; m < 4; m++)
#pragma unroll
      for (int n = 0; n < 4; n++)
        acc[m][n] = __builtin_amdgcn_mfma_f32_16x16x32_bf16(af[m], bfr[n], acc[m][n], 0, 0, 0);
  }

  if (MODE == 0) {
#pragma unroll
    for (int m = 0; m < 4; m++)
#pragma unroll
      for (int n = 0; n < 4; n++) {
        const int col = tn + wc*64 + n*16 + lr;
        const float bv = bias[col];
#pragma unroll
        for (int j = 0; j < 4; j++) {
          const int row = tm + wr*64 + m*16 + lhi*4 + j;
          Cout[(size_t)row * N + col] = acc[m][n][j] + bv;
        }
      }
  } else {
    const int part = tn / NC;  // 0=K, 1=Q, 2=V (uniform per block; N3C%128==0)
#pragma unroll
    for (int m = 0; m < 4; m++)
#pragma unroll
      for (int n = 0; n < 4; n++) {
        const int col = tn + wc*64 + n*16 + lr;
        const float bv = bias[col];
        const int cp = col - part * NC;
        const int h = cp >> 6, d = cp & 63;
#pragma unroll
        for (int j = 0; j < 4; j++) {
          const int row = tm + wr*64 + m*16 + lhi*4 + j;
          const int b0 = row >> 10, t = row & 1023;
          const int bh = b0 * NH + h;
          const bf16 val = (bf16)(acc[m][n][j] + bv);
          if (part == 2) {
            const size_t idx =
                ((((size_t)bh*16 + (t>>6))*4 + (d>>4))*2 + ((t>>5)&1))*512
                + (size_t)((d&15) + ((t>>3)&3)*16)*8 + (t&7);
            vp[idx] = val;
          } else {
            const size_t idx =
                (((size_t)bh*64 + (t>>4))*2 + (d>>5))*512
                + (size_t)(((d>>3)&3)*16 + (t&15))*8 + (d&7);
            if (part == 0) kp[idx] = val; else qp[idx] = val;
          }
        }
      }
  }
}

// ---------------- flash attention, causal, no-max online softmax ----------------
// One wave per block; block handles q-tiles p and 31-p sequentially (uniform
// 17 key-block iterations per block). All Q/K/V loads are coalesced 1KB
// fragment reads from the packed layouts. K register ping-pong hides K
// latency; V loads at phase top hide under QK+exp. launch_bounds(64,2):
// VGPR budget 256 (R2/R3 spill lesson).
__global__ void __launch_bounds__(64, 2)
k_attn(const bf16* __restrict__ qpack, const bf16* __restrict__ kpack,
       const bf16* __restrict__ vpack, bf16* __restrict__ y) {
  const int bh = blockIdx.x, b = bh / NH, h = bh % NH;
  const int p = blockIdx.y;            // pair index 0..15
  const int lane = threadIdx.x;
  const int lr = lane & 15, lhi = lane >> 4;
  __shared__ __align__(16) bf16 P[32][68];  // stride 136B: conflict-free

#define LOAD_K(DST, K0)                                                        \
  {                                                                            \
    _Pragma("unroll")                                                          \
    for (int g = 0; g < 4; g++)                                                \
      _Pragma("unroll")                                                        \
      for (int h2 = 0; h2 < 2; h2++)                                           \
        DST[g][h2] = *reinterpret_cast<const bf16x8*>(                         \
            kpack + (((size_t)bh*64 + ((K0)>>4) + g)*2 + h2)*512 + lane*8);    \
  }

#define ATTN_STEP(KCUR, KNXT, KB)                                              \
  {                                                                            \
    const int k0 = (KB) * 64;                                                  \
    const int kn = ((KB) + 1 < nkb) ? k0 + 64 : k0;                            \
    /* V frag loads for current tile — land under QK+exp */                    \
    bf16x8 vf[4][2];                                                           \
    _Pragma("unroll")                                                          \
    for (int dg = 0; dg < 4; dg++)                                             \
      _Pragma("unroll")                                                        \
      for (int kk = 0; kk < 2; kk++)                                           \
        vf[dg][kk] = *reinterpret_cast<const bf16x8*>(                         \
            vpack + ((((size_t)bh*16 + (k0>>6))*4 + dg)*2 + kk)*512 + lane*8); \
    /* prefetch next K tile — lands under the whole iteration */               \
    LOAD_K(KNXT, kn);                                                          \
    f32x4 S[2][4];                                                             \
    _Pragma("unroll")                                                          \
    for (int m = 0; m < 2; m++)                                                \
      _Pragma("unroll")                                                        \
      for (int g = 0; g < 4; g++) S[m][g] = (f32x4){0.f, 0.f, 0.f, 0.f};       \
    _Pragma("unroll")                                                          \
    for (int g = 0; g < 4; g++)                                                \
      _Pragma("unroll")                                                        \
      for (int m = 0; m < 2; m++) {                                            \
        S[m][g] = __builtin_amdgcn_mfma_f32_16x16x32_bf16(qf[m][0], KCUR[g][0],\
                                                          S[m][g], 0, 0, 0);   \
        S[m][g] = __builtin_amdgcn_mfma_f32_16x16x32_bf16(qf[m][1], KCUR[g][1],\
                                                          S[m][g], 0, 0, 0);   \
      }                                                                        \
    const bool need_mask = ((KB) == nkb - 1);                                  \
    _Pragma("unroll")                                                          \
    for (int m = 0; m < 2; m++)                                                \
      _Pragma("unroll")                                                        \
      for (int g = 0; g < 4; g++) {                                            \
        const int key = k0 + g*16 + lr;                                        \
        _Pragma("unroll")                                                      \
        for (int j = 0; j < 4; j++) {                                          \
          float s = S[m][g][j];                                                \
          if (need_mask) {                                                     \
            const int row = qbase + m*16 + lhi*4 + j;                          \
            if (key > row) s = -1e30f;                                         \
          }                                                                    \
          const float ppv = __expf(s);  /* no-max softmax: s<=~15, f32-safe */ \
          L[m][j] += ppv;                                                      \
          P[m*16 + lhi*4 + j][g*16 + lr] = (bf16)ppv;                          \
        }                                                                      \
      }                                                                        \
    _Pragma("unroll")                                                          \
    for (int m = 0; m < 2; m++)                                                \
      _Pragma("unroll")                                                        \
      for (int kk = 0; kk < 2; kk++) {                                         \
        bf16x8 pf = *reinterpret_cast<const bf16x8*>(&P[m*16 + lr][kk*32 + lhi*8]); \
        _Pragma("unroll")                                                      \
        for (int dg = 0; dg < 4; dg++)                                         \
          O[m][dg] = __builtin_amdgcn_mfma_f32_16x16x32_bf16(pf, vf[dg][kk],   \
                                                             O[m][dg], 0, 0, 0); \
      }                                                                        \
  }

#pragma unroll 1
  for (int half = 0; half < 2; half++) {
    const int qt = half ? (31 - p) : p;
    const int qbase = qt * 32;
    const int nkb = (qbase >> 6) + 1;  // 64-key blocks; covers keys <= row max

    bf16x8 qf[2][2];
#pragma unroll
    for (int m = 0; m < 2; m++)
#pragma unroll
      for (int kk = 0; kk < 2; kk++)
        qf[m][kk] = *reinterpret_cast<const bf16x8*>(
            qpack + (((size_t)bh*64 + (qbase>>4) + m)*2 + kk)*512 + lane*8);

    f32x4 O[2][4];
    float L[2][4];
#pragma unroll
    for (int m = 0; m < 2; m++) {
#pragma unroll
      for (int d = 0; d < 4; d++) O[m][d] = (f32x4){0.f, 0.f, 0.f, 0.f};
#pragma unroll
      for (int j = 0; j < 4; j++) L[m][j] = 0.f;
    }

    bf16x8 kfA[4][2], kfB[4][2];
    LOAD_K(kfA, 0);
    int kb = 0;
#pragma unroll 1
    while (true) {
      ATTN_STEP(kfA, kfB, kb);
      kb++;
      if (kb >= nkb) break;
      ATTN_STEP(kfB, kfA, kb);
      kb++;
      if (kb >= nkb) break;
    }

    // reduce L over the 16 lr lanes of each row group, then invert
#pragma unroll
    for (int m = 0; m < 2; m++)
#pragma unroll
      for (int j = 0; j < 4; j++) {
        float l = L[m][j];
        l += __shfl_xor(l, 1);
        l += __shfl_xor(l, 2);
        l += __shfl_xor(l, 4);
        l += __shfl_xor(l, 8);
        L[m][j] = 1.0f / l;
      }

#pragma unroll
    for (int m = 0; m < 2; m++)
#pragma unroll
      for (int dg = 0; dg < 4; dg++)
#pragma unroll
        for (int j = 0; j < 4; j++) {
          const int row = qbase + m*16 + lhi*4 + j;
          const int col = h*ND + dg*16 + lr;
          y[(size_t)(b*NT + row) * NC + col] = (bf16)(O[m][dg][j] * L[m][j]);
        }
  }
#undef ATTN_STEP
#undef LOAD_K
}

// ---------------- launcher ----------------
extern "C" void kernel_launch(void* const* d_in, const int* in_sizes, int n_in,
                              void* d_out, int out_size, void* d_ws, size_t ws_size,
                              hipStream_t stream) {
  const float* x     = (const float*)d_in[0];
  const float* W_in  = (const float*)d_in[1];
  const float* b_in  = (const float*)d_in[2];
  const float* W_out = (const float*)d_in[3];
  const float* b_out = (const float*)d_in[4];
  float* out = (float*)d_out;
  char* ws = (char*)d_ws;

  // workspace layout (bytes, 16-aligned); xb region is reused as y after GEMM1
  bf16* xb    = (bf16*)(ws + 0);          // 8192*768 bf16 = 12,582,912 (later: y)
  bf16* Wit   = (bf16*)(ws + 12582912);   // 2304*768 bf16 =  3,538,944
  bf16* Wot   = (bf16*)(ws + 16121856);   //  768*768 bf16 =  1,179,648
  bf16* qpack = (bf16*)(ws + 17301504);   // 96*64*2*512 bf16 = 12,582,912
  bf16* kpack = (bf16*)(ws + 29884416);   // 12,582,912
  bf16* vpack = (bf16*)(ws + 42467328);   // 96*16*4*2*512 bf16 = 12,582,912
  // total 55,050,240 bytes

  k_convert<<<6144, 256, 0, stream>>>(x, xb, NM * NC / 4);
  k_transpose_w<<<dim3(N3C/32, NC/32), 256, 0, stream>>>(W_in, Wit, NC, N3C);
  k_transpose_w<<<dim3(NC/32, NC/32), 256, 0, stream>>>(W_out, Wot, NC, NC);

  // GEMM1: writes Q/K/V directly in packed-fragment layouts (+bias)
  k_gemm_bt<1><<<dim3(NM/128, N3C/128), 256, 0, stream>>>(
      xb, Wit, b_in, nullptr, qpack, kpack, vpack, NM, N3C, NC);

  k_attn<<<dim3(NB*NH, 16), 64, 0, stream>>>(qpack, kpack, vpack, xb /* y */);

  // GEMM2: plain f32 output (+bias)
  k_gemm_bt<0><<<dim3(NM/128, NC/128), 256, 0, stream>>>(
      xb, Wot, b_out, out, nullptr, nullptr, nullptr, NM, NC, NC);
}

// Round 7
// 200.671 us; speedup vs baseline: 1.6710x; 1.0079x over previous
//
#include <hip/hip_runtime.h>
#include <hip/hip_bf16.h>
#include <stdint.h>

// CausalAttention fused block, MI355X gfx950.
// R6: GEMM K-loop software-pipelined — 3-buffer LDS, 2-deep prefetch with
// counted s_waitcnt vmcnt(8) (never 0 in loop; T3/T4-minimum), + both-sides
// LDS swizzle (pre-swizzled global source + swizzled ds_read col; linear
// global_load_lds dest per rule #21) killing the 8-way bank conflict.
// Attention & packed-layout epilogue unchanged from R5.

typedef __bf16 bf16;
typedef __attribute__((ext_vector_type(4))) __bf16 bf16x4;
typedef __attribute__((ext_vector_type(8))) __bf16 bf16x8;
typedef __attribute__((ext_vector_type(4))) float f32x4;

#define NB 8
#define NT 1024
#define NC 768
#define NH 12
#define ND 64
#define NM (NB*NT)     // 8192
#define N3C (3*NC)     // 2304

typedef __attribute__((address_space(1))) void as1_void;
typedef __attribute__((address_space(3))) void as3_void;

__device__ __forceinline__ void gload_lds16(const void* g, void* l) {
  __builtin_amdgcn_global_load_lds((as1_void*)g, (as3_void*)l, 16, 0, 0);
}

// Packed fragment layouts (elements, bf16):
//  kpack/qpack: frag(bh, g16 = t/16, h2 = d/32) lane l = (d%32/8)*16 + t%16,
//               elem j = d%8  -> idx = ((bh*64 + g16)*2 + h2)*512 + l*8 + j
//  vpack: frag(bh, vb = t/64, dg = d/16, kk = (t/32)%2) lane l = (d%16) +
//               ((t/8)%4)*16, elem j = t%8
//               -> idx = (((bh*16+vb)*4+dg)*2+kk)*512 + l*8 + j

// ---------------- prep: f32 -> bf16 convert (vectorized) ----------------
__global__ void k_convert(const float* __restrict__ src, bf16* __restrict__ dst, int n4) {
  int i = blockIdx.x * blockDim.x + threadIdx.x;
  if (i < n4) {
    float4 v = reinterpret_cast<const float4*>(src)[i];
    bf16x4 o = { (bf16)v.x, (bf16)v.y, (bf16)v.z, (bf16)v.w };
    reinterpret_cast<bf16x4*>(dst)[i] = o;
  }
}

// ---------------- prep: W [R][C] f32 -> W^T [C][R] bf16 ----------------
__global__ void k_transpose_w(const float* __restrict__ src, bf16* __restrict__ dst,
                              int R, int C) {
  __shared__ float tile[32][33];
  const int c0 = blockIdx.x * 32, r0 = blockIdx.y * 32;
  const int tx = threadIdx.x & 31, ty = threadIdx.x >> 5;  // 256 thr: ty 0..7
#pragma unroll
  for (int i = 0; i < 4; i++)
    tile[ty + i*8][tx] = src[(size_t)(r0 + ty + i*8) * C + c0 + tx];
  __syncthreads();
#pragma unroll
  for (int i = 0; i < 4; i++)
    dst[(size_t)(c0 + ty + i*8) * R + r0 + tx] = (bf16)tile[tx][ty + i*8];
}

// ---------------- pipelined 128x128 bf16 GEMM, B^T input ----------------
// MODE 0: C[M][N] (f32) = A@Bt^T + bias   (GEMM2)
// MODE 1: scatter into qpack/kpack/vpack (bf16) + bias  (GEMM1)
// 3-buffer LDS, 2-deep global_load_lds prefetch, counted vmcnt(8) per step.
template<int MODE>
__global__ void __launch_bounds__(256, 2)
k_gemm_bt(const bf16* __restrict__ A, const bf16* __restrict__ Bt,
          const float* __restrict__ bias, float* __restrict__ Cout,
          bf16* __restrict__ qp, bf16* __restrict__ kp,
          bf16* __restrict__ vp,
          int M, int N, int K) {
  __shared__ __align__(16) bf16 As[3][128*32];
  __shared__ __align__(16) bf16 Bs[3][128*32];
  const int tm = blockIdx.x * 128, tn = blockIdx.y * 128;
  const int tid = threadIdx.x, lane = tid & 63, w = tid >> 6;
  const int wr = w >> 1, wc = w & 1;
  const int lr = lane & 15, lhi = lane >> 4;
  const int srow = tid >> 2;
  // both-sides swizzle: stage source col pre-swizzled, read col swizzled,
  // LDS destination stays linear (global_load_lds requirement).
  const int scol = ((tid & 3) ^ ((tid >> 3) & 3)) * 8;   // elements
  const int cswz = (lhi ^ ((lr >> 1) & 3)) * 16;         // bytes
  const int nk = K / 32;

  auto stage = [&](bf16* as, bf16* bs, int kt) {
#pragma unroll
    for (int ch = 0; ch < 2; ch++) {
      gload_lds16(A + (size_t)(tm + ch*64 + srow) * K + kt + scol,
                  (char*)as + ch*4096 + tid*16);
      gload_lds16(Bt + (size_t)(tn + ch*64 + srow) * K + kt + scol,
                  (char*)bs + ch*4096 + tid*16);
    }
  };

  f32x4 acc[4][4];
#pragma unroll
  for (int m = 0; m < 4; m++)
#pragma unroll
    for (int n = 0; n < 4; n++) acc[m][n] = (f32x4){0.f, 0.f, 0.f, 0.f};

  bf16 *a0 = As[0], *a1 = As[1], *a2 = As[2];
  bf16 *b0 = Bs[0], *b1 = Bs[1], *b2 = Bs[2];
  stage(a0, b0, 0);
  stage(a1, b1, 32);
  asm volatile("s_waitcnt vmcnt(8)" ::: "memory");   // tile 0 landed
  __builtin_amdgcn_s_barrier();
  __builtin_amdgcn_sched_barrier(0);

  for (int t = 0; t < nk; ++t) {
    const int ktn = (t + 2 < nk ? t + 2 : nk - 1) * 32;  // clamp: uniform count
    stage(a2, b2, ktn);

    bf16x8 af[4], bfr[4];
#pragma unroll
    for (int m = 0; m < 4; m++)
      af[m] = *reinterpret_cast<const bf16x8*>(
          (const char*)a0 + (wr*64 + m*16 + lr) * 64 + cswz);
#pragma unroll
    for (int n = 0; n < 4; n++)
      bfr[n] = *reinterpret_cast<const bf16x8*>(
          (const char*)b0 + (wc*64 + n*16 + lr) * 64 + cswz);
#pragma unroll
    for (int m = 0; m < 4; m++)
#pragma unroll
      for (int n = 0; n < 4; n++)
        acc[m][n] = __builtin_amdgcn_mfma_f32_16x16x32_bf16(af[m], bfr[n], acc[m][n], 0, 0, 0);

    asm volatile("s_waitcnt vmcnt(8)" ::: "memory");  // oldest 8 = tile t+1
    __builtin_amdgcn_s_barrier();
    __builtin_amdgcn_sched_barrier(0);

    bf16* ra = a0; a0 = a1; a1 = a2; a2 = ra;
    bf16* rb = b0; b0 = b1; b1 = b2; b2 = rb;
  }
  asm volatile("s_waitcnt vmcnt(0)" ::: "memory");    // drain dup stages

  if (MODE == 0) {
#pragma unroll
    for (int m = 0; m < 4; m++)
#pragma unroll
      for (int n = 0; n < 4; n++) {
        const int col = tn + wc*64 + n*16 + lr;
        const float bv = bias[col];
#pragma unroll
        for (int j = 0; j < 4; j++) {
          const int row = tm + wr*64 + m*16 + lhi*4 + j;
          Cout[(size_t)row * N + col] = acc[m][n][j] + bv;
        }
      }
  } else {
    const int part = tn / NC;  // 0=K, 1=Q, 2=V (uniform per block; N3C%128==0)
#pragma unroll
    for (int m = 0; m < 4; m++)
#pragma unroll
      for (int n = 0; n < 4; n++) {
        const int col = tn + wc*64 + n*16 + lr;
        const float bv = bias[col];
        const int cp = col - part * NC;
        const int h = cp >> 6, d = cp & 63;
#pragma unroll
        for (int j = 0; j < 4; j++) {
          const int row = tm + wr*64 + m*16 + lhi*4 + j;
          const int b0i = row >> 10, t = row & 1023;
          const int bh = b0i * NH + h;
          const bf16 val = (bf16)(acc[m][n][j] + bv);
          if (part == 2) {
            const size_t idx =
                ((((size_t)bh*16 + (t>>6))*4 + (d>>4))*2 + ((t>>5)&1))*512
                + (size_t)((d&15) + ((t>>3)&3)*16)*8 + (t&7);
            vp[idx] = val;
          } else {
            const size_t idx =
                (((size_t)bh*64 + (t>>4))*2 + (d>>5))*512
                + (size_t)(((d>>3)&3)*16 + (t&15))*8 + (d&7);
            if (part == 0) kp[idx] = val; else qp[idx] = val;
          }
        }
      }
  }
}

// ---------------- flash attention, causal, no-max online softmax ----------------
// One wave per block; block handles q-tiles p and 31-p sequentially (uniform
// 17 key-block iterations per block). All Q/K/V loads are coalesced 1KB
// fragment reads from the packed layouts. K register ping-pong hides K
// latency; V loads at phase top hide under QK+exp. launch_bounds(64,2):
// VGPR budget 256 (R2/R3 spill lesson).
__global__ void __launch_bounds__(64, 2)
k_attn(const bf16* __restrict__ qpack, const bf16* __restrict__ kpack,
       const bf16* __restrict__ vpack, bf16* __restrict__ y) {
  const int bh = blockIdx.x, b = bh / NH, h = bh % NH;
  const int p = blockIdx.y;            // pair index 0..15
  const int lane = threadIdx.x;
  const int lr = lane & 15, lhi = lane >> 4;
  __shared__ __align__(16) bf16 P[32][68];  // stride 136B: conflict-free

#define LOAD_K(DST, K0)                                                        \
  {                                                                            \
    _Pragma("unroll")                                                          \
    for (int g = 0; g < 4; g++)                                                \
      _Pragma("unroll")                                                        \
      for (int h2 = 0; h2 < 2; h2++)                                           \
        DST[g][h2] = *reinterpret_cast<const bf16x8*>(                         \
            kpack + (((size_t)bh*64 + ((K0)>>4) + g)*2 + h2)*512 + lane*8);    \
  }

#define ATTN_STEP(KCUR, KNXT, KB)                                              \
  {                                                                            \
    const int k0 = (KB) * 64;                                                  \
    const int kn = ((KB) + 1 < nkb) ? k0 + 64 : k0;                            \
    /* V frag loads for current tile — land under QK+exp */                    \
    bf16x8 vf[4][2];                                                           \
    _Pragma("unroll")                                                          \
    for (int dg = 0; dg < 4; dg++)                                             \
      _Pragma("unroll")                                                        \
      for (int kk = 0; kk < 2; kk++)                                           \
        vf[dg][kk] = *reinterpret_cast<const bf16x8*>(                         \
            vpack + ((((size_t)bh*16 + (k0>>6))*4 + dg)*2 + kk)*512 + lane*8); \
    /* prefetch next K tile — lands under the whole iteration */               \
    LOAD_K(KNXT, kn);                                                          \
    f32x4 S[2][4];                                                             \
    _Pragma("unroll")                                                          \
    for (int m = 0; m < 2; m++)                                                \
      _Pragma("unroll")                                                        \
      for (int g = 0; g < 4; g++) S[m][g] = (f32x4){0.f, 0.f, 0.f, 0.f};       \
    _Pragma("unroll")                                                          \
    for (int g = 0; g < 4; g++)                                                \
      _Pragma("unroll")                                                        \
      for (int m = 0; m < 2; m++) {                                            \
        S[m][g] = __builtin_amdgcn_mfma_f32_16x16x32_bf16(qf[m][0], KCUR[g][0],\
                                                          S[m][g], 0, 0, 0);   \
        S[m][g] = __builtin_amdgcn_mfma_f32_16x16x32_bf16(qf[m][1], KCUR[g][1],\
                                                          S[m][g], 0, 0, 0);   \
      }                                                                        \
    const bool need_mask = ((KB) == nkb - 1);                                  \
    _Pragma("unroll")                                                          \
    for (int m = 0; m < 2; m++)                                                \
      _Pragma("unroll")                                                        \
      for (int g = 0; g < 4; g++) {                                            \
        const int key = k0 + g*16 + lr;                                        \
        _Pragma("unroll")                                                      \
        for (int j = 0; j < 4; j++) {                                          \
          float s = S[m][g][j];                                                \
          if (need_mask) {                                                     \
            const int row = qbase + m*16 + lhi*4 + j;                          \
            if (key > row) s = -1e30f;                                         \
          }                                                                    \
          const float ppv = __expf(s);  /* no-max softmax: s<=~15, f32-safe */ \
          L[m][j] += ppv;                                                      \
          P[m*16 + lhi*4 + j][g*16 + lr] = (bf16)ppv;                          \
        }                                                                      \
      }                                                                        \
    _Pragma("unroll")                                                          \
    for (int m = 0; m < 2; m++)                                                \
      _Pragma("unroll")                                                        \
      for (int kk = 0; kk < 2; kk++) {                                         \
        bf16x8 pf = *reinterpret_cast<const bf16x8*>(&P[m*16 + lr][kk*32 + lhi*8]); \
        _Pragma("unroll")                                                      \
        for (int dg = 0; dg < 4; dg++)                                         \
          O[m][dg] = __builtin_amdgcn_mfma_f32_16x16x32_bf16(pf, vf[dg][kk],   \
                                                             O[m][dg], 0, 0, 0); \
      }                                                                        \
  }

#pragma unroll 1
  for (int half = 0; half < 2; half++) {
    const int qt = half ? (31 - p) : p;
    const int qbase = qt * 32;
    const int nkb = (qbase >> 6) + 1;  // 64-key blocks; covers keys <= row max

    bf16x8 qf[2][2];
#pragma unroll
    for (int m = 0; m < 2; m++)
#pragma unroll
      for (int kk = 0; kk < 2; kk++)
        qf[m][kk] = *reinterpret_cast<const bf16x8*>(
            qpack + (((size_t)bh*64 + (qbase>>4) + m)*2 + kk)*512 + lane*8);

    f32x4 O[2][4];
    float L[2][4];
#pragma unroll
    for (int m = 0; m < 2; m++) {
#pragma unroll
      for (int d = 0; d < 4; d++) O[m][d] = (f32x4){0.f, 0.f, 0.f, 0.f};
#pragma unroll
      for (int j = 0; j < 4; j++) L[m][j] = 0.f;
    }

    bf16x8 kfA[4][2], kfB[4][2];
    LOAD_K(kfA, 0);
    int kb = 0;
#pragma unroll 1
    while (true) {
      ATTN_STEP(kfA, kfB, kb);
      kb++;
      if (kb >= nkb) break;
      ATTN_STEP(kfB, kfA, kb);
      kb++;
      if (kb >= nkb) break;
    }

    // reduce L over the 16 lr lanes of each row group, then invert
#pragma unroll
    for (int m = 0; m < 2; m++)
#pragma unroll
      for (int j = 0; j < 4; j++) {
        float l = L[m][j];
        l += __shfl_xor(l, 1);
        l += __shfl_xor(l, 2);
        l += __shfl_xor(l, 4);
        l += __shfl_xor(l, 8);
        L[m][j] = 1.0f / l;
      }

#pragma unroll
    for (int m = 0; m < 2; m++)
#pragma unroll
      for (int dg = 0; dg < 4; dg++)
#pragma unroll
        for (int j = 0; j < 4; j++) {
          const int row = qbase + m*16 + lhi*4 + j;
          const int col = h*ND + dg*16 + lr;
          y[(size_t)(b*NT + row) * NC + col] = (bf16)(O[m][dg][j] * L[m][j]);
        }
  }
#undef ATTN_STEP
#undef LOAD_K
}

// ---------------- launcher ----------------
extern "C" void kernel_launch(void* const* d_in, const int* in_sizes, int n_in,
                              void* d_out, int out_size, void* d_ws, size_t ws_size,
                              hipStream_t stream) {
  const float* x     = (const float*)d_in[0];
  const float* W_in  = (const float*)d_in[1];
  const float* b_in  = (const float*)d_in[2];
  const float* W_out = (const float*)d_in[3];
  const float* b_out = (const float*)d_in[4];
  float* out = (float*)d_out;
  char* ws = (char*)d_ws;

  // workspace layout (bytes, 16-aligned); xb region is reused as y after GEMM1
  bf16* xb    = (bf16*)(ws + 0);          // 8192*768 bf16 = 12,582,912 (later: y)
  bf16* Wit   = (bf16*)(ws + 12582912);   // 2304*768 bf16 =  3,538,944
  bf16* Wot   = (bf16*)(ws + 16121856);   //  768*768 bf16 =  1,179,648
  bf16* qpack = (bf16*)(ws + 17301504);   // 96*64*2*512 bf16 = 12,582,912
  bf16* kpack = (bf16*)(ws + 29884416);   // 12,582,912
  bf16* vpack = (bf16*)(ws + 42467328);   // 96*16*4*2*512 bf16 = 12,582,912
  // total 55,050,240 bytes

  k_convert<<<6144, 256, 0, stream>>>(x, xb, NM * NC / 4);
  k_transpose_w<<<dim3(N3C/32, NC/32), 256, 0, stream>>>(W_in, Wit, NC, N3C);
  k_transpose_w<<<dim3(NC/32, NC/32), 256, 0, stream>>>(W_out, Wot, NC, NC);

  // GEMM1: writes Q/K/V directly in packed-fragment layouts (+bias)
  k_gemm_bt<1><<<dim3(NM/128, N3C/128), 256, 0, stream>>>(
      xb, Wit, b_in, nullptr, qpack, kpack, vpack, NM, N3C, NC);

  k_attn<<<dim3(NB*NH, 16), 64, 0, stream>>>(qpack, kpack, vpack, xb /* y */);

  // GEMM2: plain f32 output (+bias)
  k_gemm_bt<0><<<dim3(NM/128, NC/128), 256, 0, stream>>>(
      xb, Wot, b_out, out, nullptr, nullptr, nullptr, NM, NC, NC);
}

// Round 8
// 198.445 us; speedup vs baseline: 1.6897x; 1.0112x over previous
//
#include <hip/hip_runtime.h>
#include <hip/hip_bf16.h>
#include <stdint.h>

// CausalAttention fused block, MI355X gfx950.
// R7: GEMM pipeline corrected — counted vmcnt BEFORE the LDS reads
// (stage(t+2) -> vmcnt(2*LOADS) -> barrier -> read+MFMA -> barrier), fixing
// the R6 read-before-land race AND making the wait actually hide latency.
// Occupancy raised: GEMM1 (256,3) = 3 blocks/CU; GEMM2 retiled to 64x128
// (grid 768 blocks, (256,4) = 4 blocks/CU). Attention unchanged from R5.

typedef __bf16 bf16;
typedef __attribute__((ext_vector_type(4))) __bf16 bf16x4;
typedef __attribute__((ext_vector_type(8))) __bf16 bf16x8;
typedef __attribute__((ext_vector_type(4))) float f32x4;

#define NB 8
#define NT 1024
#define NC 768
#define NH 12
#define ND 64
#define NM (NB*NT)     // 8192
#define N3C (3*NC)     // 2304

typedef __attribute__((address_space(1))) void as1_void;
typedef __attribute__((address_space(3))) void as3_void;

__device__ __forceinline__ void gload_lds16(const void* g, void* l) {
  __builtin_amdgcn_global_load_lds((as1_void*)g, (as3_void*)l, 16, 0, 0);
}

// Packed fragment layouts (elements, bf16):
//  kpack/qpack: frag(bh, g16 = t/16, h2 = d/32) lane l = (d%32/8)*16 + t%16,
//               elem j = d%8  -> idx = ((bh*64 + g16)*2 + h2)*512 + l*8 + j
//  vpack: frag(bh, vb = t/64, dg = d/16, kk = (t/32)%2) lane l = (d%16) +
//               ((t/8)%4)*16, elem j = t%8
//               -> idx = (((bh*16+vb)*4+dg)*2+kk)*512 + l*8 + j

// ---------------- prep: f32 -> bf16 convert (vectorized) ----------------
__global__ void k_convert(const float* __restrict__ src, bf16* __restrict__ dst, int n4) {
  int i = blockIdx.x * blockDim.x + threadIdx.x;
  if (i < n4) {
    float4 v = reinterpret_cast<const float4*>(src)[i];
    bf16x4 o = { (bf16)v.x, (bf16)v.y, (bf16)v.z, (bf16)v.w };
    reinterpret_cast<bf16x4*>(dst)[i] = o;
  }
}

// ---------------- prep: W [R][C] f32 -> W^T [C][R] bf16 ----------------
__global__ void k_transpose_w(const float* __restrict__ src, bf16* __restrict__ dst,
                              int R, int C) {
  __shared__ float tile[32][33];
  const int c0 = blockIdx.x * 32, r0 = blockIdx.y * 32;
  const int tx = threadIdx.x & 31, ty = threadIdx.x >> 5;  // 256 thr: ty 0..7
#pragma unroll
  for (int i = 0; i < 4; i++)
    tile[ty + i*8][tx] = src[(size_t)(r0 + ty + i*8) * C + c0 + tx];
  __syncthreads();
#pragma unroll
  for (int i = 0; i < 4; i++)
    dst[(size_t)(c0 + ty + i*8) * R + r0 + tx] = (bf16)tile[tx][ty + i*8];
}

// ---------------- pipelined TMx128 bf16 GEMM, B^T input ----------------
// MODE 0: C[M][N] (f32) = A@Bt^T + bias   (GEMM2, TM=64)
// MODE 1: scatter into qpack/kpack/vpack (bf16) + bias  (GEMM1, TM=128)
// 3-buffer LDS, 2-deep prefetch, counted vmcnt BEFORE reads (T3/T4 pattern).
template<int MODE, int TM>
__global__ void __launch_bounds__(256, (TM == 128 ? 3 : 4))
k_gemm_bt(const bf16* __restrict__ A, const bf16* __restrict__ Bt,
          const float* __restrict__ bias, float* __restrict__ Cout,
          bf16* __restrict__ qp, bf16* __restrict__ kp,
          bf16* __restrict__ vp,
          int M, int N, int K) {
  constexpr int ACH = TM / 64;        // A stage chunks per buffer (1 or 2)
  constexpr int MF  = TM / 32;        // m-fragments per wave (2 or 4)
  constexpr int WM  = TM / 2;         // wave m-stride
  __shared__ __align__(16) bf16 As[3][TM*32];
  __shared__ __align__(16) bf16 Bs[3][128*32];
  const int tm = blockIdx.x * TM, tn = blockIdx.y * 128;
  const int tid = threadIdx.x, lane = tid & 63, w = tid >> 6;
  const int wr = w >> 1, wc = w & 1;
  const int lr = lane & 15, lhi = lane >> 4;
  const int srow = tid >> 2;
  // both-sides swizzle: stage source col pre-swizzled, read col swizzled,
  // LDS destination stays linear (global_load_lds requirement).
  const int scol = ((tid & 3) ^ ((tid >> 3) & 3)) * 8;   // elements
  const int cswz = (lhi ^ ((lr >> 1) & 3)) * 16;         // bytes
  const int nk = K / 32;

  auto stage = [&](bf16* as, bf16* bs, int kt) {
#pragma unroll
    for (int ch = 0; ch < ACH; ch++)
      gload_lds16(A + (size_t)(tm + ch*64 + srow) * K + kt + scol,
                  (char*)as + ch*4096 + tid*16);
#pragma unroll
    for (int ch = 0; ch < 2; ch++)
      gload_lds16(Bt + (size_t)(tn + ch*64 + srow) * K + kt + scol,
                  (char*)bs + ch*4096 + tid*16);
  };

  f32x4 acc[MF][4];
#pragma unroll
  for (int m = 0; m < MF; m++)
#pragma unroll
    for (int n = 0; n < 4; n++) acc[m][n] = (f32x4){0.f, 0.f, 0.f, 0.f};

  bf16 *a0 = As[0], *a1 = As[1], *a2 = As[2];
  bf16 *b0 = Bs[0], *b1 = Bs[1], *b2 = Bs[2];
  stage(a0, b0, 0);
  stage(a1, b1, 32);

  for (int t = 0; t < nk; ++t) {
    const int ktn = (t + 2 < nk ? t + 2 : nk - 1) * 32;  // clamp: uniform count
    stage(a2, b2, ktn);
    // wait: everything older than the newest 2 stages retired => tile t landed
    if constexpr (ACH == 2) asm volatile("s_waitcnt vmcnt(8)" ::: "memory");
    else                    asm volatile("s_waitcnt vmcnt(6)" ::: "memory");
    __builtin_amdgcn_s_barrier();   // all waves' tile-t loads landed

    bf16x8 af[MF], bfr[4];
#pragma unroll
    for (int m = 0; m < MF; m++)
      af[m] = *reinterpret_cast<const bf16x8*>(
          (const char*)a0 + (wr*WM + m*16 + lr) * 64 + cswz);
#pragma unroll
    for (int n = 0; n < 4; n++)
      bfr[n] = *reinterpret_cast<const bf16x8*>(
          (const char*)b0 + (wc*64 + n*16 + lr) * 64 + cswz);
#pragma unroll
    for (int m = 0; m < MF; m++)
#pragma unroll
      for (int n = 0; n < 4; n++)
        acc[m][n] = __builtin_amdgcn_mfma_f32_16x16x32_bf16(af[m], bfr[n], acc[m][n], 0, 0, 0);

    __builtin_amdgcn_s_barrier();   // reads of tile t done before re-stage

    bf16* ra = a0; a0 = a1; a1 = a2; a2 = ra;
    bf16* rb = b0; b0 = b1; b1 = b2; b2 = rb;
  }
  asm volatile("s_waitcnt vmcnt(0)" ::: "memory");    // drain dup stages

  if (MODE == 0) {
#pragma unroll
    for (int m = 0; m < MF; m++)
#pragma unroll
      for (int n = 0; n < 4; n++) {
        const int col = tn + wc*64 + n*16 + lr;
        const float bv = bias[col];
#pragma unroll
        for (int j = 0; j < 4; j++) {
          const int row = tm + wr*WM + m*16 + lhi*4 + j;
          Cout[(size_t)row * N + col] = acc[m][n][j] + bv;
        }
      }
  } else {
    const int part = tn / NC;  // 0=K, 1=Q, 2=V (uniform per block; N3C%128==0)
#pragma unroll
    for (int m = 0; m < MF; m++)
#pragma unroll
      for (int n = 0; n < 4; n++) {
        const int col = tn + wc*64 + n*16 + lr;
        const float bv = bias[col];
        const int cp = col - part * NC;
        const int h = cp >> 6, d = cp & 63;
#pragma unroll
        for (int j = 0; j < 4; j++) {
          const int row = tm + wr*WM + m*16 + lhi*4 + j;
          const int b0i = row >> 10, t = row & 1023;
          const int bh = b0i * NH + h;
          const bf16 val = (bf16)(acc[m][n][j] + bv);
          if (part == 2) {
            const size_t idx =
                ((((size_t)bh*16 + (t>>6))*4 + (d>>4))*2 + ((t>>5)&1))*512
                + (size_t)((d&15) + ((t>>3)&3)*16)*8 + (t&7);
            vp[idx] = val;
          } else {
            const size_t idx =
                (((size_t)bh*64 + (t>>4))*2 + (d>>5))*512
                + (size_t)(((d>>3)&3)*16 + (t&15))*8 + (d&7);
            if (part == 0) kp[idx] = val; else qp[idx] = val;
          }
        }
      }
  }
}

// ---------------- flash attention, causal, no-max online softmax ----------------
// One wave per block; block handles q-tiles p and 31-p sequentially (uniform
// 17 key-block iterations per block). All Q/K/V loads are coalesced 1KB
// fragment reads from the packed layouts. K register ping-pong hides K
// latency; V loads at phase top hide under QK+exp. launch_bounds(64,2):
// VGPR budget 256 (R2/R3 spill lesson).
__global__ void __launch_bounds__(64, 2)
k_attn(const bf16* __restrict__ qpack, const bf16* __restrict__ kpack,
       const bf16* __restrict__ vpack, bf16* __restrict__ y) {
  const int bh = blockIdx.x, b = bh / NH, h = bh % NH;
  const int p = blockIdx.y;            // pair index 0..15
  const int lane = threadIdx.x;
  const int lr = lane & 15, lhi = lane >> 4;
  __shared__ __align__(16) bf16 P[32][68];  // stride 136B: conflict-free

#define LOAD_K(DST, K0)                                                        \
  {                                                                            \
    _Pragma("unroll")                                                          \
    for (int g = 0; g < 4; g++)                                                \
      _Pragma("unroll")                                                        \
      for (int h2 = 0; h2 < 2; h2++)                                           \
        DST[g][h2] = *reinterpret_cast<const bf16x8*>(                         \
            kpack + (((size_t)bh*64 + ((K0)>>4) + g)*2 + h2)*512 + lane*8);    \
  }

#define ATTN_STEP(KCUR, KNXT, KB)                                              \
  {                                                                            \
    const int k0 = (KB) * 64;                                                  \
    const int kn = ((KB) + 1 < nkb) ? k0 + 64 : k0;                            \
    /* V frag loads for current tile — land under QK+exp */                    \
    bf16x8 vf[4][2];                                                           \
    _Pragma("unroll")                                                          \
    for (int dg = 0; dg < 4; dg++)                                             \
      _Pragma("unroll")                                                        \
      for (int kk = 0; kk < 2; kk++)                                           \
        vf[dg][kk] = *reinterpret_cast<const bf16x8*>(                         \
            vpack + ((((size_t)bh*16 + (k0>>6))*4 + dg)*2 + kk)*512 + lane*8); \
    /* prefetch next K tile — lands under the whole iteration */               \
    LOAD_K(KNXT, kn);                                                          \
    f32x4 S[2][4];                                                             \
    _Pragma("unroll")                                                          \
    for (int m = 0; m < 2; m++)                                                \
      _Pragma("unroll")                                                        \
      for (int g = 0; g < 4; g++) S[m][g] = (f32x4){0.f, 0.f, 0.f, 0.f};       \
    _Pragma("unroll")                                                          \
    for (int g = 0; g < 4; g++)                                                \
      _Pragma("unroll")                                                        \
      for (int m = 0; m < 2; m++) {                                            \
        S[m][g] = __builtin_amdgcn_mfma_f32_16x16x32_bf16(qf[m][0], KCUR[g][0],\
                                                          S[m][g], 0, 0, 0);   \
        S[m][g] = __builtin_amdgcn_mfma_f32_16x16x32_bf16(qf[m][1], KCUR[g][1],\
                                                          S[m][g], 0, 0, 0);   \
      }                                                                        \
    const bool need_mask = ((KB) == nkb - 1);                                  \
    _Pragma("unroll")                                                          \
    for (int m = 0; m < 2; m++)                                                \
      _Pragma("unroll")                                                        \
      for (int g = 0; g < 4; g++) {                                            \
        const int key = k0 + g*16 + lr;                                        \
        _Pragma("unroll")                                                      \
        for (int j = 0; j < 4; j++) {                                          \
          float s = S[m][g][j];                                                \
          if (need_mask) {                                                     \
            const int row = qbase + m*16 + lhi*4 + j;                          \
            if (key > row) s = -1e30f;                                         \
          }                                                                    \
          const float ppv = __expf(s);  /* no-max softmax: s<=~15, f32-safe */ \
          L[m][j] += ppv;                                                      \
          P[m*16 + lhi*4 + j][g*16 + lr] = (bf16)ppv;                          \
        }                                                                      \
      }                                                                        \
    _Pragma("unroll")                                                          \
    for (int m = 0; m < 2; m++)                                                \
      _Pragma("unroll")                                                        \
      for (int kk = 0; kk < 2; kk++) {                                         \
        bf16x8 pf = *reinterpret_cast<const bf16x8*>(&P[m*16 + lr][kk*32 + lhi*8]); \
        _Pragma("unroll")                                                      \
        for (int dg = 0; dg < 4; dg++)                                         \
          O[m][dg] = __builtin_amdgcn_mfma_f32_16x16x32_bf16(pf, vf[dg][kk],   \
                                                             O[m][dg], 0, 0, 0); \
      }                                                                        \
  }

#pragma unroll 1
  for (int half = 0; half < 2; half++) {
    const int qt = half ? (31 - p) : p;
    const int qbase = qt * 32;
    const int nkb = (qbase >> 6) + 1;  // 64-key blocks; covers keys <= row max

    bf16x8 qf[2][2];
#pragma unroll
    for (int m = 0; m < 2; m++)
#pragma unroll
      for (int kk = 0; kk < 2; kk++)
        qf[m][kk] = *reinterpret_cast<const bf16x8*>(
            qpack + (((size_t)bh*64 + (qbase>>4) + m)*2 + kk)*512 + lane*8);

    f32x4 O[2][4];
    float L[2][4];
#pragma unroll
    for (int m = 0; m < 2; m++) {
#pragma unroll
      for (int d = 0; d < 4; d++) O[m][d] = (f32x4){0.f, 0.f, 0.f, 0.f};
#pragma unroll
      for (int j = 0; j < 4; j++) L[m][j] = 0.f;
    }

    bf16x8 kfA[4][2], kfB[4][2];
    LOAD_K(kfA, 0);
    int kb = 0;
#pragma unroll 1
    while (true) {
      ATTN_STEP(kfA, kfB, kb);
      kb++;
      if (kb >= nkb) break;
      ATTN_STEP(kfB, kfA, kb);
      kb++;
      if (kb >= nkb) break;
    }

    // reduce L over the 16 lr lanes of each row group, then invert
#pragma unroll
    for (int m = 0; m < 2; m++)
#pragma unroll
      for (int j = 0; j < 4; j++) {
        float l = L[m][j];
        l += __shfl_xor(l, 1);
        l += __shfl_xor(l, 2);
        l += __shfl_xor(l, 4);
        l += __shfl_xor(l, 8);
        L[m][j] = 1.0f / l;
      }

#pragma unroll
    for (int m = 0; m < 2; m++)
#pragma unroll
      for (int dg = 0; dg < 4; dg++)
#pragma unroll
        for (int j = 0; j < 4; j++) {
          const int row = qbase + m*16 + lhi*4 + j;
          const int col = h*ND + dg*16 + lr;
          y[(size_t)(b*NT + row) * NC + col] = (bf16)(O[m][dg][j] * L[m][j]);
        }
  }
#undef ATTN_STEP
#undef LOAD_K
}

// ---------------- launcher ----------------
extern "C" void kernel_launch(void* const* d_in, const int* in_sizes, int n_in,
                              void* d_out, int out_size, void* d_ws, size_t ws_size,
                              hipStream_t stream) {
  const float* x     = (const float*)d_in[0];
  const float* W_in  = (const float*)d_in[1];
  const float* b_in  = (const float*)d_in[2];
  const float* W_out = (const float*)d_in[3];
  const float* b_out = (const float*)d_in[4];
  float* out = (float*)d_out;
  char* ws = (char*)d_ws;

  // workspace layout (bytes, 16-aligned); xb region is reused as y after GEMM1
  bf16* xb    = (bf16*)(ws + 0);          // 8192*768 bf16 = 12,582,912 (later: y)
  bf16* Wit   = (bf16*)(ws + 12582912);   // 2304*768 bf16 =  3,538,944
  bf16* Wot   = (bf16*)(ws + 16121856);   //  768*768 bf16 =  1,179,648
  bf16* qpack = (bf16*)(ws + 17301504);   // 96*64*2*512 bf16 = 12,582,912
  bf16* kpack = (bf16*)(ws + 29884416);   // 12,582,912
  bf16* vpack = (bf16*)(ws + 42467328);   // 96*16*4*2*512 bf16 = 12,582,912
  // total 55,050,240 bytes

  k_convert<<<6144, 256, 0, stream>>>(x, xb, NM * NC / 4);
  k_transpose_w<<<dim3(N3C/32, NC/32), 256, 0, stream>>>(W_in, Wit, NC, N3C);
  k_transpose_w<<<dim3(NC/32, NC/32), 256, 0, stream>>>(W_out, Wot, NC, NC);

  // GEMM1: writes Q/K/V directly in packed-fragment layouts (+bias)
  k_gemm_bt<1,128><<<dim3(NM/128, N3C/128), 256, 0, stream>>>(
      xb, Wit, b_in, nullptr, qpack, kpack, vpack, NM, N3C, NC);

  k_attn<<<dim3(NB*NH, 16), 64, 0, stream>>>(qpack, kpack, vpack, xb /* y */);

  // GEMM2: plain f32 output (+bias), 64x128 tiles -> 768 blocks
  k_gemm_bt<0,64><<<dim3(NM/64, NC/128), 256, 0, stream>>>(
      xb, Wot, b_out, out, nullptr, nullptr, nullptr, NM, NC, NC);
}